// Round 12
// baseline (48.060 us; speedup 1.0000x reference)
//
#include <hip/hip_runtime.h>
#include <hip/hip_bf16.h>
#include <math.h>

#define SEQ   2048
#define CDIM  1024
#define HD    64
#define NROW  16384           // B*T
// log2(e)/32  (softmax scale C^-0.5 = 1/32 folded into the exp2 multiplier)
#define CEXP 0.04508422002778112f

typedef float  f32x4  __attribute__((ext_vector_type(4)));
typedef __bf16 bf16x8 __attribute__((ext_vector_type(8)));
typedef int    i32x4  __attribute__((ext_vector_type(4)));

#define AS1 __attribute__((address_space(1)))
#define AS3 __attribute__((address_space(3)))

// RNE-pack two f32 into one dword of 2 bf16
static __device__ __forceinline__ unsigned pk2(float a, float b) {
    unsigned ua = __builtin_bit_cast(unsigned, a);
    unsigned ub = __builtin_bit_cast(unsigned, b);
    ua += 0x7fffu + ((ua >> 16) & 1u);
    ub += 0x7fffu + ((ub >> 16) & 1u);
    return (ua >> 16) | (ub & 0xffff0000u);
}

static __device__ __forceinline__ bf16x8 cvt8(f32x4 lo, f32x4 hi) {
    i32x4 w = { (int)pk2(lo[0], lo[1]), (int)pk2(lo[2], lo[3]),
                (int)pk2(hi[0], hi[1]), (int)pk2(hi[2], hi[3]) };
    return __builtin_bit_cast(bf16x8, w);
}

// ---------------- kernel 0: W fp32 -> bf16 (one-shot, 128 KB) -------------------
__global__ __launch_bounds__(256) void wconv_kernel(const float* __restrict__ W,
                                                    unsigned* __restrict__ Wb) {
    const int i = blockIdx.x * 256 + threadIdx.x;   // 16384 threads x 4 floats
    float4 v = *(const float4*)(W + (size_t)i * 4);
    uint2 p = make_uint2(pk2(v.x, v.y), pk2(v.z, v.w));
    *(uint2*)(Wb + (size_t)i * 2) = p;
}

// ---------------- kernel 1: K = x @ W_k^T (forced-ILP register pipeline) --------
// 256 blocks x 256 threads (4 waves, 1 block/CU). Wave = 16 rows x 64 heads,
// K-loop = 32 steps of 32. W (128 KB bf16) in LDS once (pre-swizzled DMA).
// x: 8-deep inline-asm register ring, counted vmcnt, zero main-loop barriers.
// NEW (r12): Ko stored via per-wave LDS transpose -> 2 coalesced dwordx4 stores.
template<int S>
struct XProl {
    static __device__ __forceinline__ void run(f32x4 (&XA)[8], f32x4 (&XB)[8],
                                               unsigned long long xa) {
        constexpr int OFF = S * 128;
        asm volatile("global_load_dwordx4 %0, %2, off offset:%3\n\t"
                     "global_load_dwordx4 %1, %2, off offset:%4"
                     : "=&v"(XA[S]), "=&v"(XB[S])
                     : "v"(xa), "n"(OFF), "n"(OFF + 16)
                     : "memory");
        if constexpr (S + 1 < 8) XProl<S + 1>::run(XA, XB, xa);
    }
};

template<int T>
struct XLoop {
    static __device__ __forceinline__ void run(f32x4 (&XA)[8], f32x4 (&XB)[8],
                                               unsigned long long xa,
                                               const char* const (&wp)[4][2],
                                               f32x4 (&acc)[4]) {
        constexpr int WT = (T < 24) ? 14 : 2 * (31 - T);
        asm volatile("s_waitcnt vmcnt(%0)" :: "n"(WT) : "memory");
        __builtin_amdgcn_sched_barrier(0);
        bf16x8 A = cvt8(XA[T & 7], XB[T & 7]);
        #pragma unroll
        for (int nt = 0; nt < 4; ++nt) {
            bf16x8 B = *(const bf16x8*)(wp[nt][T & 1] + (T >> 1) * 128);
            acc[nt] = __builtin_amdgcn_mfma_f32_16x16x32_bf16(A, B, acc[nt], 0, 0, 0);
        }
        if constexpr (T < 24) {
            constexpr int OFF = (T + 8) * 128;
            asm volatile("global_load_dwordx4 %0, %2, off offset:%3\n\t"
                         "global_load_dwordx4 %1, %2, off offset:%4"
                         : "=&v"(XA[T & 7]), "=&v"(XB[T & 7])
                         : "v"(xa), "n"(OFF), "n"(OFF + 16)
                         : "memory");
        }
        if constexpr (T + 1 < 32) XLoop<T + 1>::run(XA, XB, xa, wp, acc);
    }
};

__global__ __launch_bounds__(256, 1) void proj_kernel(const float* __restrict__ x,
                                                      const unsigned short* __restrict__ Wb,
                                                      unsigned short* __restrict__ Ko,
                                                      uint2* __restrict__ KV2) {
    __shared__ __align__(16) char wlds[131072];            // W bf16 [64][1024], swizzled
    __shared__ __align__(16) unsigned short tb[4][16][64]; // per-wave Ko transpose (8 KB)

    const int tid = threadIdx.x;
    const int wid = tid >> 6, l = tid & 63, lm = l & 15, lg = l >> 4;
    const int bid = blockIdx.x;

    // ---- one-time W stage: linear LDS dest, pre-swizzled global source --------
    #pragma unroll
    for (int j = 0; j < 32; ++j) {
        int d = j * 4096 + tid * 16;               // linear dest byte
        int row = d >> 11, inner = d & 2047;
        int sin_ = inner ^ ((row & 7) << 4);       // involution, bits 4-6
        const unsigned short* src = Wb + (size_t)row * CDIM + (sin_ >> 1);
        __builtin_amdgcn_global_load_lds((const AS1 void*)src,
                                         (AS3 void*)(wlds + j * 4096 + wid * 1024),
                                         16, 0, 0);
    }

    // ---- x pipeline prologue: 8 steps in flight (16 dwordx4) ------------------
    const int row = bid * 64 + wid * 16 + lm;
    unsigned long long xa =
        (unsigned long long)(const void*)(x + (size_t)row * CDIM + lg * 8);
    f32x4 XA[8], XB[8];
    XProl<0>::run(XA, XB, xa);

    // wait W retired (32 oldest), x stays in flight; then one raw barrier
    asm volatile("s_waitcnt vmcnt(16)" ::: "memory");
    __builtin_amdgcn_sched_barrier(0);
    __builtin_amdgcn_s_barrier();
    __builtin_amdgcn_sched_barrier(0);

    // ---- per-lane W B-frag bases: byte(ks) = (ks>>1)*128 + ((ks&1)^hb)*64 + L --
    const int hb = (lm >> 2) & 1;
    const int L  = ((lg ^ (lm & 3)) << 4);
    const char* wp[4][2];
    #pragma unroll
    for (int nt = 0; nt < 4; ++nt) {
        const char* base = wlds + (nt * 16 + lm) * 2048;
        wp[nt][0] = base + hb * 64 + L;            // even ks
        wp[nt][1] = base + (1 - hb) * 64 + L;      // odd ks
    }

    f32x4 acc[4];
    acc[0] = acc[1] = acc[2] = acc[3] = (f32x4){0.f, 0.f, 0.f, 0.f};
    XLoop<0>::run(XA, XB, xa, wp, acc);

    // ---- Ko via wave-local LDS transpose (no barrier: own tb[wid] only) -------
    #pragma unroll
    for (int nt = 0; nt < 4; ++nt)
        #pragma unroll
        for (int r = 0; r < 4; ++r)
            tb[wid][lg * 4 + r][nt * 16 + lm] =
                (unsigned short)(pk2(acc[nt][r], 0.f) & 0xffffu);
    const size_t m0r = (size_t)bid * 64 + wid * 16;
    {
        const char* tbase = (const char*)&tb[wid][0][0];
        i32x4 v0 = *(const i32x4*)(tbase + l * 16);          // rows 0..7
        i32x4 v1 = *(const i32x4*)(tbase + 1024 + l * 16);   // rows 8..15
        char* kbase = (char*)(Ko + m0r * HD);
        *(i32x4*)(kbase + l * 16)        = v0;
        *(i32x4*)(kbase + 1024 + l * 16) = v1;
    }
    const size_t g = (size_t)bid * 4 + wid;
    #pragma unroll
    for (int nt = 0; nt < 4; ++nt)
        KV2[(g * 4 + nt) * 64 + l] =
            make_uint2(pk2(acc[nt][0], acc[nt][1]), pk2(acc[nt][2], acc[nt][3]));
}

// ---------------- kernel 2: causal flash attention, paired kv-tiles -------------
struct KT { bf16x8 ka0, ka1; uint2 bv[4]; };
struct KT2 { bf16x8 kaA0, kaA1, kaB0, kaB1; i32x4 bv[4]; };

static __device__ __forceinline__ KT load_tile(const unsigned short* __restrict__ Kb,
                                               const uint2* __restrict__ KVb,
                                               int kt, int lm, int lg, int l) {
    KT t;
    const unsigned short* ar = Kb + (size_t)(kt * 16 + lm) * HD + lg * 8;
    t.ka0 = *(const bf16x8*)ar;
    t.ka1 = *(const bf16x8*)(ar + 32);
    const uint2* vp = KVb + (size_t)kt * 256 + l;
    #pragma unroll
    for (int nt = 0; nt < 4; ++nt) t.bv[nt] = vp[nt * 64];
    return t;
}

// pair (kt, kt+4): PV B-frags fill all 8 k-slots (A rows in 0..3, B rows in 4..7)
static __device__ __forceinline__ KT2 load_pair(const unsigned short* __restrict__ Kb,
                                                const uint2* __restrict__ KVb,
                                                int kt, int lm, int lg, int l) {
    KT2 t;
    const unsigned short* arA = Kb + (size_t)(kt * 16 + lm) * HD + lg * 8;
    const unsigned short* arB = arA + 4 * 16 * HD;
    t.kaA0 = *(const bf16x8*)arA;
    t.kaA1 = *(const bf16x8*)(arA + 32);
    t.kaB0 = *(const bf16x8*)arB;
    t.kaB1 = *(const bf16x8*)(arB + 32);
    const uint2* vpA = KVb + (size_t)kt * 256 + l;
    const uint2* vpB = vpA + 4 * 256;
    #pragma unroll
    for (int nt = 0; nt < 4; ++nt) {
        uint2 a = vpA[nt * 64], b = vpB[nt * 64];
        t.bv[nt] = (i32x4){ (int)a.x, (int)a.y, (int)b.x, (int)b.y };
    }
    return t;
}

static __device__ __forceinline__ void proc_tile(const KT& t, bf16x8 bq0, bf16x8 bq1,
                                                 bool diag, int lm, int lg,
                                                 float& ls, f32x4 o[4]) {
    f32x4 s4 = (f32x4){0.f, 0.f, 0.f, 0.f};
    s4 = __builtin_amdgcn_mfma_f32_16x16x32_bf16(t.ka0, bq0, s4, 0, 0, 0);
    s4 = __builtin_amdgcn_mfma_f32_16x16x32_bf16(t.ka1, bq1, s4, 0, 0, 0);
    float s0 = s4[0], s1 = s4[1], s2 = s4[2], s3 = s4[3];
    if (diag) {
        const int kb = lg * 4;
        s0 = (kb + 0 > lm) ? -1e30f : s0;
        s1 = (kb + 1 > lm) ? -1e30f : s1;
        s2 = (kb + 2 > lm) ? -1e30f : s2;
        s3 = (kb + 3 > lm) ? -1e30f : s3;
    }
    float p0 = __builtin_amdgcn_exp2f(s0 * CEXP);
    float p1 = __builtin_amdgcn_exp2f(s1 * CEXP);
    float p2 = __builtin_amdgcn_exp2f(s2 * CEXP);
    float p3 = __builtin_amdgcn_exp2f(s3 * CEXP);
    ls += (p0 + p1) + (p2 + p3);
    i32x4 pw = { (int)pk2(p0, p1), (int)pk2(p2, p3), 0, 0 };
    bf16x8 pa = __builtin_bit_cast(bf16x8, pw);
    #pragma unroll
    for (int nt = 0; nt < 4; ++nt) {
        i32x4 vw = { (int)t.bv[nt].x, (int)t.bv[nt].y, 0, 0 };
        bf16x8 bvx = __builtin_bit_cast(bf16x8, vw);
        o[nt] = __builtin_amdgcn_mfma_f32_16x16x32_bf16(pa, bvx, o[nt], 0, 0, 0);
    }
}

static __device__ __forceinline__ void proc_pair(const KT2& t, bf16x8 bq0, bf16x8 bq1,
                                                 bool diagB, int lm, int lg,
                                                 float& ls, f32x4 o[4]) {
    f32x4 sa = (f32x4){0.f, 0.f, 0.f, 0.f}, sb = sa;
    sa = __builtin_amdgcn_mfma_f32_16x16x32_bf16(t.kaA0, bq0, sa, 0, 0, 0);
    sa = __builtin_amdgcn_mfma_f32_16x16x32_bf16(t.kaA1, bq1, sa, 0, 0, 0);
    sb = __builtin_amdgcn_mfma_f32_16x16x32_bf16(t.kaB0, bq0, sb, 0, 0, 0);
    sb = __builtin_amdgcn_mfma_f32_16x16x32_bf16(t.kaB1, bq1, sb, 0, 0, 0);
    float b0 = sb[0], b1 = sb[1], b2 = sb[2], b3 = sb[3];
    if (diagB) {
        const int kb = lg * 4;
        b0 = (kb + 0 > lm) ? -1e30f : b0;
        b1 = (kb + 1 > lm) ? -1e30f : b1;
        b2 = (kb + 2 > lm) ? -1e30f : b2;
        b3 = (kb + 3 > lm) ? -1e30f : b3;
    }
    float pa0 = __builtin_amdgcn_exp2f(sa[0] * CEXP);
    float pa1 = __builtin_amdgcn_exp2f(sa[1] * CEXP);
    float pa2 = __builtin_amdgcn_exp2f(sa[2] * CEXP);
    float pa3 = __builtin_amdgcn_exp2f(sa[3] * CEXP);
    float pb0 = __builtin_amdgcn_exp2f(b0 * CEXP);
    float pb1 = __builtin_amdgcn_exp2f(b1 * CEXP);
    float pb2 = __builtin_amdgcn_exp2f(b2 * CEXP);
    float pb3 = __builtin_amdgcn_exp2f(b3 * CEXP);
    ls += ((pa0 + pa1) + (pa2 + pa3)) + ((pb0 + pb1) + (pb2 + pb3));
    i32x4 pw = { (int)pk2(pa0, pa1), (int)pk2(pa2, pa3),
                 (int)pk2(pb0, pb1), (int)pk2(pb2, pb3) };
    bf16x8 pa8 = __builtin_bit_cast(bf16x8, pw);
    #pragma unroll
    for (int nt = 0; nt < 4; ++nt) {
        bf16x8 bvx = __builtin_bit_cast(bf16x8, t.bv[nt]);
        o[nt] = __builtin_amdgcn_mfma_f32_16x16x32_bf16(pa8, bvx, o[nt], 0, 0, 0);
    }
}

// wave w processes kv tiles kt ≡ w (mod 4) of q-tile qt, two tiles per iteration.
static __device__ __forceinline__ void flash_qtile(const unsigned short* __restrict__ Kb,
                                                   const uint2* __restrict__ KVb,
                                                   int qt, int w, int lm, int lg, int l,
                                                   float& ls, f32x4 o[4]) {
    if (qt < w) return;
    const unsigned short* qr = Kb + (size_t)(qt * 16 + lm) * HD + lg * 8;
    bf16x8 bq0 = *(const bf16x8*)qr;
    bf16x8 bq1 = *(const bf16x8*)(qr + 32);
    const int n = ((qt - w) >> 2) + 1;             // tile count
    const bool diagL = (w + 4 * (n - 1)) == qt;    // last tile on the diagonal?
    int kt = w;
    if (n == 1) {
        KT S = load_tile(Kb, KVb, kt, lm, lg, l);
        proc_tile(S, bq0, bq1, diagL, lm, lg, ls, o);
        return;
    }
    KT2 A = load_pair(Kb, KVb, kt, lm, lg, l);
    int rem = n;
    while (rem >= 4) {
        KT2 B = load_pair(Kb, KVb, kt + 8, lm, lg, l);
        proc_pair(A, bq0, bq1, false, lm, lg, ls, o);
        A = B; kt += 8; rem -= 2;
    }
    if (rem == 3) {
        KT S = load_tile(Kb, KVb, kt + 8, lm, lg, l);
        proc_pair(A, bq0, bq1, false, lm, lg, ls, o);
        proc_tile(S, bq0, bq1, diagL, lm, lg, ls, o);
    } else {
        proc_pair(A, bq0, bq1, diagL, lm, lg, ls, o);
    }
}

// 512 blocks x 256 threads (4 waves). Block = (batch, causal pair {i, 127-i}).
__global__ __launch_bounds__(256, 2) void attn_kernel(const unsigned short* __restrict__ K,
                                                      const uint2* __restrict__ KV2,
                                                      float* __restrict__ out) {
    __shared__ float oS[2][4][16][68];
    __shared__ float lS[2][4][16];
    const int tid = threadIdx.x;
    const int wid = tid >> 6, l = tid & 63, lm = l & 15, lg = l >> 4;
    const int b = blockIdx.x >> 6, i = blockIdx.x & 63;
    const unsigned short* Kb  = K   + (size_t)b * SEQ * HD;
    const uint2*          KVb = KV2 + (size_t)b * 128 * 256;

    #pragma unroll
    for (int s = 0; s < 2; ++s) {
        const int qt = s ? (127 - i) : i;
        float ls = 0.f;
        f32x4 o[4];
        o[0] = o[1] = o[2] = o[3] = (f32x4){0.f, 0.f, 0.f, 0.f};
        flash_qtile(Kb, KVb, qt, wid, lm, lg, l, ls, o);
        ls += __shfl_xor(ls, 16);
        ls += __shfl_xor(ls, 32);
        #pragma unroll
        for (int nt = 0; nt < 4; ++nt)
            #pragma unroll
            for (int r = 0; r < 4; ++r)
                oS[s][wid][lg * 4 + r][nt * 16 + lm] = o[nt][r];
        if (lg == 0) lS[s][wid][lm] = ls;
    }
    __syncthreads();

    const int slot = tid >> 7;
    const int row  = (tid >> 3) & 15;
    const int cg   = tid & 7;
    const int qt   = slot ? (127 - i) : i;
    float L = lS[slot][0][row] + lS[slot][1][row] + lS[slot][2][row] + lS[slot][3][row];
    const float inv = 1.f / L;
    f32x4 a0 = (f32x4){0.f, 0.f, 0.f, 0.f}, a1 = a0;
    #pragma unroll
    for (int w = 0; w < 4; ++w) {
        a0 += *(const f32x4*)&oS[slot][w][row][cg * 8];
        a1 += *(const f32x4*)&oS[slot][w][row][cg * 8 + 4];
    }
    float* op = out + ((size_t)b * SEQ + qt * 16 + row) * HD + cg * 8;
    *(f32x4*)op       = a0 * inv;
    *(f32x4*)(op + 4) = a1 * inv;
}

extern "C" void kernel_launch(void* const* d_in, const int* in_sizes, int n_in,
                              void* d_out, int out_size, void* d_ws, size_t ws_size,
                              hipStream_t stream) {
    const float* x  = (const float*)d_in[0];   // [8,2048,1024] fp32
    const float* Wk = (const float*)d_in[1];   // [64,1024] fp32
    float* o        = (float*)d_out;           // [8,2048,64] fp32
    unsigned short* Kp = (unsigned short*)d_ws;              // bf16 K [16384][64] (2 MB)
    unsigned short* Wb = Kp + (size_t)NROW * HD;             // bf16 W [64][1024] (128 KB)
    uint2* KV2 = (uint2*)(Wb + (size_t)HD * CDIM);           // PV frags (2 MB)

    wconv_kernel<<<64, 256, 0, stream>>>(Wk, (unsigned*)Wb);
    proj_kernel<<<256, 256, 0, stream>>>(x, Wb, Kp, KV2);
    attn_kernel<<<512, 256, 0, stream>>>(Kp, KV2, o);
}

// Round 14
// 45.795 us; speedup vs baseline: 1.0494x; 1.0494x over previous
//
#include <hip/hip_runtime.h>
#include <hip/hip_bf16.h>
#include <math.h>

#define SEQ   2048
#define CDIM  1024
#define HD    64
#define NROW  16384           // B*T
// log2(e)/32  (softmax scale C^-0.5 = 1/32 folded into the exp2 multiplier)
#define CEXP 0.04508422002778112f

typedef float  f32x4  __attribute__((ext_vector_type(4)));
typedef __bf16 bf16x8 __attribute__((ext_vector_type(8)));
typedef int    i32x4  __attribute__((ext_vector_type(4)));

#define AS1 __attribute__((address_space(1)))
#define AS3 __attribute__((address_space(3)))

// RNE-pack two f32 into one dword of 2 bf16
static __device__ __forceinline__ unsigned pk2(float a, float b) {
    unsigned ua = __builtin_bit_cast(unsigned, a);
    unsigned ub = __builtin_bit_cast(unsigned, b);
    ua += 0x7fffu + ((ua >> 16) & 1u);
    ub += 0x7fffu + ((ub >> 16) & 1u);
    return (ua >> 16) | (ub & 0xffff0000u);
}

static __device__ __forceinline__ bf16x8 cvt8(f32x4 lo, f32x4 hi) {
    i32x4 w = { (int)pk2(lo[0], lo[1]), (int)pk2(lo[2], lo[3]),
                (int)pk2(hi[0], hi[1]), (int)pk2(hi[2], hi[3]) };
    return __builtin_bit_cast(bf16x8, w);
}

// ---------------- kernel 1: K = x @ W_k^T (forced-ILP register pipeline) --------
// 256 blocks x 256 threads (4 waves, 1 block/CU). Wave = 16 rows x 64 heads,
// K-loop = 32 steps of 32. W fp32 -> swizzled bf16 LDS inside this kernel
// (r13-fix: ALL 64 rows staged — r13 bug was rows 16..63 uninitialized).
// x: 8-deep inline-asm register ring, counted vmcnt, zero main-loop barriers.
// Ko stored via per-wave LDS transpose -> 2 coalesced dwordx4 stores (r12).
template<int S>
struct XProl {
    static __device__ __forceinline__ void run(f32x4 (&XA)[8], f32x4 (&XB)[8],
                                               unsigned long long xa) {
        constexpr int OFF = S * 128;
        asm volatile("global_load_dwordx4 %0, %2, off offset:%3\n\t"
                     "global_load_dwordx4 %1, %2, off offset:%4"
                     : "=&v"(XA[S]), "=&v"(XB[S])
                     : "v"(xa), "n"(OFF), "n"(OFF + 16)
                     : "memory");
        if constexpr (S + 1 < 8) XProl<S + 1>::run(XA, XB, xa);
    }
};

template<int T>
struct XLoop {
    static __device__ __forceinline__ void run(f32x4 (&XA)[8], f32x4 (&XB)[8],
                                               unsigned long long xa,
                                               const char* const (&wp)[4][2],
                                               f32x4 (&acc)[4]) {
        constexpr int WT = (T < 24) ? 14 : 2 * (31 - T);
        asm volatile("s_waitcnt vmcnt(%0)" :: "n"(WT) : "memory");
        __builtin_amdgcn_sched_barrier(0);
        bf16x8 A = cvt8(XA[T & 7], XB[T & 7]);
        #pragma unroll
        for (int nt = 0; nt < 4; ++nt) {
            bf16x8 B = *(const bf16x8*)(wp[nt][T & 1] + (T >> 1) * 128);
            acc[nt] = __builtin_amdgcn_mfma_f32_16x16x32_bf16(A, B, acc[nt], 0, 0, 0);
        }
        if constexpr (T < 24) {
            constexpr int OFF = (T + 8) * 128;
            asm volatile("global_load_dwordx4 %0, %2, off offset:%3\n\t"
                         "global_load_dwordx4 %1, %2, off offset:%4"
                         : "=&v"(XA[T & 7]), "=&v"(XB[T & 7])
                         : "v"(xa), "n"(OFF), "n"(OFF + 16)
                         : "memory");
        }
        if constexpr (T + 1 < 32) XLoop<T + 1>::run(XA, XB, xa, wp, acc);
    }
};

__global__ __launch_bounds__(256, 1) void proj_kernel(const float* __restrict__ x,
                                                      const float* __restrict__ W,
                                                      unsigned short* __restrict__ Ko,
                                                      uint2* __restrict__ KV2) {
    __shared__ __align__(16) char wlds[131072];            // W bf16 [64][1024], swizzled
    __shared__ __align__(16) unsigned short tb[4][16][64]; // per-wave Ko transpose (8 KB)

    const int tid = threadIdx.x;
    const int wid = tid >> 6, l = tid & 63, lm = l & 15, lg = l >> 4;
    const int bid = blockIdx.x;

    // ---- W fp32 -> bf16 -> swizzled LDS (ALL 64 rows; 4 chunks of 16) ---------
    // row r: thread tid holds floats [tid*4, tid*4+4) -> bf16 bytes a = tid*8;
    // involution identical to r11 DMA: lds[row][a ^ ((row&7)<<4)] = Wbf16[row][a]
    #pragma unroll
    for (int c = 0; c < 4; ++c) {
        float4 wv[16];
        #pragma unroll
        for (int j = 0; j < 16; ++j)
            wv[j] = *(const float4*)(W + ((size_t)(c * 16 + j) * 256 + tid) * 4);
        #pragma unroll
        for (int j = 0; j < 16; ++j) {
            const int r = c * 16 + j;
            uint2 p = make_uint2(pk2(wv[j].x, wv[j].y), pk2(wv[j].z, wv[j].w));
            *(uint2*)(wlds + r * 2048 + ((tid * 8) ^ ((r & 7) << 4))) = p;
        }
    }

    // ---- x pipeline prologue: 8 steps in flight (16 dwordx4) ------------------
    const int row = bid * 64 + wid * 16 + lm;
    unsigned long long xa =
        (unsigned long long)(const void*)(x + (size_t)row * CDIM + lg * 8);
    f32x4 XA[8], XB[8];
    XProl<0>::run(XA, XB, xa);

    // ds_writes drained for all waves, then raw barrier; x stays in flight
    asm volatile("s_waitcnt lgkmcnt(0)" ::: "memory");
    __builtin_amdgcn_sched_barrier(0);
    __builtin_amdgcn_s_barrier();
    __builtin_amdgcn_sched_barrier(0);

    // ---- per-lane W B-frag bases: byte(ks) = (ks>>1)*128 + ((ks&1)^hb)*64 + L --
    const int hb = (lm >> 2) & 1;
    const int L  = ((lg ^ (lm & 3)) << 4);
    const char* wp[4][2];
    #pragma unroll
    for (int nt = 0; nt < 4; ++nt) {
        const char* base = wlds + (nt * 16 + lm) * 2048;
        wp[nt][0] = base + hb * 64 + L;            // even ks
        wp[nt][1] = base + (1 - hb) * 64 + L;      // odd ks
    }

    f32x4 acc[4];
    acc[0] = acc[1] = acc[2] = acc[3] = (f32x4){0.f, 0.f, 0.f, 0.f};
    XLoop<0>::run(XA, XB, xa, wp, acc);

    // ---- Ko via wave-local LDS transpose (no barrier: own tb[wid] only) -------
    #pragma unroll
    for (int nt = 0; nt < 4; ++nt)
        #pragma unroll
        for (int r = 0; r < 4; ++r)
            tb[wid][lg * 4 + r][nt * 16 + lm] =
                (unsigned short)(pk2(acc[nt][r], 0.f) & 0xffffu);
    const size_t m0r = (size_t)bid * 64 + wid * 16;
    {
        const char* tbase = (const char*)&tb[wid][0][0];
        i32x4 v0 = *(const i32x4*)(tbase + l * 16);          // rows 0..7
        i32x4 v1 = *(const i32x4*)(tbase + 1024 + l * 16);   // rows 8..15
        char* kbase = (char*)(Ko + m0r * HD);
        *(i32x4*)(kbase + l * 16)        = v0;
        *(i32x4*)(kbase + 1024 + l * 16) = v1;
    }
    const size_t g = (size_t)bid * 4 + wid;
    #pragma unroll
    for (int nt = 0; nt < 4; ++nt)
        KV2[(g * 4 + nt) * 64 + l] =
            make_uint2(pk2(acc[nt][0], acc[nt][1]), pk2(acc[nt][2], acc[nt][3]));
}

// ---------------- kernel 2: causal flash attention, paired kv-tiles (frozen) ----
struct KT { bf16x8 ka0, ka1; uint2 bv[4]; };
struct KT2 { bf16x8 kaA0, kaA1, kaB0, kaB1; i32x4 bv[4]; };

static __device__ __forceinline__ KT load_tile(const unsigned short* __restrict__ Kb,
                                               const uint2* __restrict__ KVb,
                                               int kt, int lm, int lg, int l) {
    KT t;
    const unsigned short* ar = Kb + (size_t)(kt * 16 + lm) * HD + lg * 8;
    t.ka0 = *(const bf16x8*)ar;
    t.ka1 = *(const bf16x8*)(ar + 32);
    const uint2* vp = KVb + (size_t)kt * 256 + l;
    #pragma unroll
    for (int nt = 0; nt < 4; ++nt) t.bv[nt] = vp[nt * 64];
    return t;
}

static __device__ __forceinline__ KT2 load_pair(const unsigned short* __restrict__ Kb,
                                                const uint2* __restrict__ KVb,
                                                int kt, int lm, int lg, int l) {
    KT2 t;
    const unsigned short* arA = Kb + (size_t)(kt * 16 + lm) * HD + lg * 8;
    const unsigned short* arB = arA + 4 * 16 * HD;
    t.kaA0 = *(const bf16x8*)arA;
    t.kaA1 = *(const bf16x8*)(arA + 32);
    t.kaB0 = *(const bf16x8*)arB;
    t.kaB1 = *(const bf16x8*)(arB + 32);
    const uint2* vpA = KVb + (size_t)kt * 256 + l;
    const uint2* vpB = vpA + 4 * 256;
    #pragma unroll
    for (int nt = 0; nt < 4; ++nt) {
        uint2 a = vpA[nt * 64], b = vpB[nt * 64];
        t.bv[nt] = (i32x4){ (int)a.x, (int)a.y, (int)b.x, (int)b.y };
    }
    return t;
}

static __device__ __forceinline__ void proc_tile(const KT& t, bf16x8 bq0, bf16x8 bq1,
                                                 bool diag, int lm, int lg,
                                                 float& ls, f32x4 o[4]) {
    f32x4 s4 = (f32x4){0.f, 0.f, 0.f, 0.f};
    s4 = __builtin_amdgcn_mfma_f32_16x16x32_bf16(t.ka0, bq0, s4, 0, 0, 0);
    s4 = __builtin_amdgcn_mfma_f32_16x16x32_bf16(t.ka1, bq1, s4, 0, 0, 0);
    float s0 = s4[0], s1 = s4[1], s2 = s4[2], s3 = s4[3];
    if (diag) {
        const int kb = lg * 4;
        s0 = (kb + 0 > lm) ? -1e30f : s0;
        s1 = (kb + 1 > lm) ? -1e30f : s1;
        s2 = (kb + 2 > lm) ? -1e30f : s2;
        s3 = (kb + 3 > lm) ? -1e30f : s3;
    }
    float p0 = __builtin_amdgcn_exp2f(s0 * CEXP);
    float p1 = __builtin_amdgcn_exp2f(s1 * CEXP);
    float p2 = __builtin_amdgcn_exp2f(s2 * CEXP);
    float p3 = __builtin_amdgcn_exp2f(s3 * CEXP);
    ls += (p0 + p1) + (p2 + p3);
    i32x4 pw = { (int)pk2(p0, p1), (int)pk2(p2, p3), 0, 0 };
    bf16x8 pa = __builtin_bit_cast(bf16x8, pw);
    #pragma unroll
    for (int nt = 0; nt < 4; ++nt) {
        i32x4 vw = { (int)t.bv[nt].x, (int)t.bv[nt].y, 0, 0 };
        bf16x8 bvx = __builtin_bit_cast(bf16x8, vw);
        o[nt] = __builtin_amdgcn_mfma_f32_16x16x32_bf16(pa, bvx, o[nt], 0, 0, 0);
    }
}

static __device__ __forceinline__ void proc_pair(const KT2& t, bf16x8 bq0, bf16x8 bq1,
                                                 bool diagB, int lm, int lg,
                                                 float& ls, f32x4 o[4]) {
    f32x4 sa = (f32x4){0.f, 0.f, 0.f, 0.f}, sb = sa;
    sa = __builtin_amdgcn_mfma_f32_16x16x32_bf16(t.kaA0, bq0, sa, 0, 0, 0);
    sa = __builtin_amdgcn_mfma_f32_16x16x32_bf16(t.kaA1, bq1, sa, 0, 0, 0);
    sb = __builtin_amdgcn_mfma_f32_16x16x32_bf16(t.kaB0, bq0, sb, 0, 0, 0);
    sb = __builtin_amdgcn_mfma_f32_16x16x32_bf16(t.kaB1, bq1, sb, 0, 0, 0);
    float b0 = sb[0], b1 = sb[1], b2 = sb[2], b3 = sb[3];
    if (diagB) {
        const int kb = lg * 4;
        b0 = (kb + 0 > lm) ? -1e30f : b0;
        b1 = (kb + 1 > lm) ? -1e30f : b1;
        b2 = (kb + 2 > lm) ? -1e30f : b2;
        b3 = (kb + 3 > lm) ? -1e30f : b3;
    }
    float pa0 = __builtin_amdgcn_exp2f(sa[0] * CEXP);
    float pa1 = __builtin_amdgcn_exp2f(sa[1] * CEXP);
    float pa2 = __builtin_amdgcn_exp2f(sa[2] * CEXP);
    float pa3 = __builtin_amdgcn_exp2f(sa[3] * CEXP);
    float pb0 = __builtin_amdgcn_exp2f(b0 * CEXP);
    float pb1 = __builtin_amdgcn_exp2f(b1 * CEXP);
    float pb2 = __builtin_amdgcn_exp2f(b2 * CEXP);
    float pb3 = __builtin_amdgcn_exp2f(b3 * CEXP);
    ls += ((pa0 + pa1) + (pa2 + pa3)) + ((pb0 + pb1) + (pb2 + pb3));
    i32x4 pw = { (int)pk2(pa0, pa1), (int)pk2(pa2, pa3),
                 (int)pk2(pb0, pb1), (int)pk2(pb2, pb3) };
    bf16x8 pa8 = __builtin_bit_cast(bf16x8, pw);
    #pragma unroll
    for (int nt = 0; nt < 4; ++nt) {
        bf16x8 bvx = __builtin_bit_cast(bf16x8, t.bv[nt]);
        o[nt] = __builtin_amdgcn_mfma_f32_16x16x32_bf16(pa8, bvx, o[nt], 0, 0, 0);
    }
}

static __device__ __forceinline__ void flash_qtile(const unsigned short* __restrict__ Kb,
                                                   const uint2* __restrict__ KVb,
                                                   int qt, int w, int lm, int lg, int l,
                                                   float& ls, f32x4 o[4]) {
    if (qt < w) return;
    const unsigned short* qr = Kb + (size_t)(qt * 16 + lm) * HD + lg * 8;
    bf16x8 bq0 = *(const bf16x8*)qr;
    bf16x8 bq1 = *(const bf16x8*)(qr + 32);
    const int n = ((qt - w) >> 2) + 1;             // tile count
    const bool diagL = (w + 4 * (n - 1)) == qt;    // last tile on the diagonal?
    int kt = w;
    if (n == 1) {
        KT S = load_tile(Kb, KVb, kt, lm, lg, l);
        proc_tile(S, bq0, bq1, diagL, lm, lg, ls, o);
        return;
    }
    KT2 A = load_pair(Kb, KVb, kt, lm, lg, l);
    int rem = n;
    while (rem >= 4) {
        KT2 B = load_pair(Kb, KVb, kt + 8, lm, lg, l);
        proc_pair(A, bq0, bq1, false, lm, lg, ls, o);
        A = B; kt += 8; rem -= 2;
    }
    if (rem == 3) {
        KT S = load_tile(Kb, KVb, kt + 8, lm, lg, l);
        proc_pair(A, bq0, bq1, false, lm, lg, ls, o);
        proc_tile(S, bq0, bq1, diagL, lm, lg, ls, o);
    } else {
        proc_pair(A, bq0, bq1, diagL, lm, lg, ls, o);
    }
}

__global__ __launch_bounds__(256, 2) void attn_kernel(const unsigned short* __restrict__ K,
                                                      const uint2* __restrict__ KV2,
                                                      float* __restrict__ out) {
    __shared__ float oS[2][4][16][68];
    __shared__ float lS[2][4][16];
    const int tid = threadIdx.x;
    const int wid = tid >> 6, l = tid & 63, lm = l & 15, lg = l >> 4;
    const int b = blockIdx.x >> 6, i = blockIdx.x & 63;
    const unsigned short* Kb  = K   + (size_t)b * SEQ * HD;
    const uint2*          KVb = KV2 + (size_t)b * 128 * 256;

    #pragma unroll
    for (int s = 0; s < 2; ++s) {
        const int qt = s ? (127 - i) : i;
        float ls = 0.f;
        f32x4 o[4];
        o[0] = o[1] = o[2] = o[3] = (f32x4){0.f, 0.f, 0.f, 0.f};
        flash_qtile(Kb, KVb, qt, wid, lm, lg, l, ls, o);
        ls += __shfl_xor(ls, 16);
        ls += __shfl_xor(ls, 32);
        #pragma unroll
        for (int nt = 0; nt < 4; ++nt)
            #pragma unroll
            for (int r = 0; r < 4; ++r)
                oS[s][wid][lg * 4 + r][nt * 16 + lm] = o[nt][r];
        if (lg == 0) lS[s][wid][lm] = ls;
    }
    __syncthreads();

    const int slot = tid >> 7;
    const int row  = (tid >> 3) & 15;
    const int cg   = tid & 7;
    const int qt   = slot ? (127 - i) : i;
    float L = lS[slot][0][row] + lS[slot][1][row] + lS[slot][2][row] + lS[slot][3][row];
    const float inv = 1.f / L;
    f32x4 a0 = (f32x4){0.f, 0.f, 0.f, 0.f}, a1 = a0;
    #pragma unroll
    for (int w = 0; w < 4; ++w) {
        a0 += *(const f32x4*)&oS[slot][w][row][cg * 8];
        a1 += *(const f32x4*)&oS[slot][w][row][cg * 8 + 4];
    }
    float* op = out + ((size_t)b * SEQ + qt * 16 + row) * HD + cg * 8;
    *(f32x4*)op       = a0 * inv;
    *(f32x4*)(op + 4) = a1 * inv;
}

extern "C" void kernel_launch(void* const* d_in, const int* in_sizes, int n_in,
                              void* d_out, int out_size, void* d_ws, size_t ws_size,
                              hipStream_t stream) {
    const float* x  = (const float*)d_in[0];   // [8,2048,1024] fp32
    const float* Wk = (const float*)d_in[1];   // [64,1024] fp32
    float* o        = (float*)d_out;           // [8,2048,64] fp32
    unsigned short* Kp = (unsigned short*)d_ws;              // bf16 K [16384][64] (2 MB)
    uint2* KV2 = (uint2*)(Kp + (size_t)NROW * HD);           // PV frags (2 MB)

    proj_kernel<<<256, 256, 0, stream>>>(x, Wk, Kp, KV2);
    attn_kernel<<<512, 256, 0, stream>>>(Kp, KV2, o);
}

// Round 15
// 38.603 us; speedup vs baseline: 1.2450x; 1.1863x over previous
//
#include <hip/hip_runtime.h>
#include <hip/hip_bf16.h>
#include <math.h>

#define SEQ   2048
#define CDIM  1024
#define HD    64
#define NROW  16384           // B*T
// log2(e)/32  (softmax scale C^-0.5 = 1/32 folded into the exp2 multiplier)
#define CEXP 0.04508422002778112f

typedef float  f32x4  __attribute__((ext_vector_type(4)));
typedef __bf16 bf16x8 __attribute__((ext_vector_type(8)));
typedef int    i32x4  __attribute__((ext_vector_type(4)));

#define AS1 __attribute__((address_space(1)))
#define AS3 __attribute__((address_space(3)))

// RNE-pack two f32 into one dword of 2 bf16
static __device__ __forceinline__ unsigned pk2(float a, float b) {
    unsigned ua = __builtin_bit_cast(unsigned, a);
    unsigned ub = __builtin_bit_cast(unsigned, b);
    ua += 0x7fffu + ((ua >> 16) & 1u);
    ub += 0x7fffu + ((ub >> 16) & 1u);
    return (ua >> 16) | (ub & 0xffff0000u);
}

static __device__ __forceinline__ bf16x8 cvt8(f32x4 lo, f32x4 hi) {
    i32x4 w = { (int)pk2(lo[0], lo[1]), (int)pk2(lo[2], lo[3]),
                (int)pk2(hi[0], hi[1]), (int)pk2(hi[2], hi[3]) };
    return __builtin_bit_cast(bf16x8, w);
}

// ---------------- kernel 1: K = x @ W_k^T (forced-ILP register pipeline) --------
// Frozen from r14. 256 blocks x 256 threads (4 waves, 1 block/CU).
template<int S>
struct XProl {
    static __device__ __forceinline__ void run(f32x4 (&XA)[8], f32x4 (&XB)[8],
                                               unsigned long long xa) {
        constexpr int OFF = S * 128;
        asm volatile("global_load_dwordx4 %0, %2, off offset:%3\n\t"
                     "global_load_dwordx4 %1, %2, off offset:%4"
                     : "=&v"(XA[S]), "=&v"(XB[S])
                     : "v"(xa), "n"(OFF), "n"(OFF + 16)
                     : "memory");
        if constexpr (S + 1 < 8) XProl<S + 1>::run(XA, XB, xa);
    }
};

template<int T>
struct XLoop {
    static __device__ __forceinline__ void run(f32x4 (&XA)[8], f32x4 (&XB)[8],
                                               unsigned long long xa,
                                               const char* const (&wp)[4][2],
                                               f32x4 (&acc)[4]) {
        constexpr int WT = (T < 24) ? 14 : 2 * (31 - T);
        asm volatile("s_waitcnt vmcnt(%0)" :: "n"(WT) : "memory");
        __builtin_amdgcn_sched_barrier(0);
        bf16x8 A = cvt8(XA[T & 7], XB[T & 7]);
        #pragma unroll
        for (int nt = 0; nt < 4; ++nt) {
            bf16x8 B = *(const bf16x8*)(wp[nt][T & 1] + (T >> 1) * 128);
            acc[nt] = __builtin_amdgcn_mfma_f32_16x16x32_bf16(A, B, acc[nt], 0, 0, 0);
        }
        if constexpr (T < 24) {
            constexpr int OFF = (T + 8) * 128;
            asm volatile("global_load_dwordx4 %0, %2, off offset:%3\n\t"
                         "global_load_dwordx4 %1, %2, off offset:%4"
                         : "=&v"(XA[T & 7]), "=&v"(XB[T & 7])
                         : "v"(xa), "n"(OFF), "n"(OFF + 16)
                         : "memory");
        }
        if constexpr (T + 1 < 32) XLoop<T + 1>::run(XA, XB, xa, wp, acc);
    }
};

__global__ __launch_bounds__(256, 1) void proj_kernel(const float* __restrict__ x,
                                                      const float* __restrict__ W,
                                                      unsigned short* __restrict__ Ko,
                                                      uint2* __restrict__ KV2) {
    __shared__ __align__(16) char wlds[131072];            // W bf16 [64][1024], swizzled
    __shared__ __align__(16) unsigned short tb[4][16][64]; // per-wave Ko transpose (8 KB)

    const int tid = threadIdx.x;
    const int wid = tid >> 6, l = tid & 63, lm = l & 15, lg = l >> 4;
    const int bid = blockIdx.x;

    // ---- W fp32 -> bf16 -> swizzled LDS (ALL 64 rows; 4 chunks of 16) ---------
    #pragma unroll
    for (int c = 0; c < 4; ++c) {
        float4 wv[16];
        #pragma unroll
        for (int j = 0; j < 16; ++j)
            wv[j] = *(const float4*)(W + ((size_t)(c * 16 + j) * 256 + tid) * 4);
        #pragma unroll
        for (int j = 0; j < 16; ++j) {
            const int r = c * 16 + j;
            uint2 p = make_uint2(pk2(wv[j].x, wv[j].y), pk2(wv[j].z, wv[j].w));
            *(uint2*)(wlds + r * 2048 + ((tid * 8) ^ ((r & 7) << 4))) = p;
        }
    }

    // ---- x pipeline prologue: 8 steps in flight (16 dwordx4) ------------------
    const int row = bid * 64 + wid * 16 + lm;
    unsigned long long xa =
        (unsigned long long)(const void*)(x + (size_t)row * CDIM + lg * 8);
    f32x4 XA[8], XB[8];
    XProl<0>::run(XA, XB, xa);

    asm volatile("s_waitcnt lgkmcnt(0)" ::: "memory");
    __builtin_amdgcn_sched_barrier(0);
    __builtin_amdgcn_s_barrier();
    __builtin_amdgcn_sched_barrier(0);

    // ---- per-lane W B-frag bases: byte(ks) = (ks>>1)*128 + ((ks&1)^hb)*64 + L --
    const int hb = (lm >> 2) & 1;
    const int L  = ((lg ^ (lm & 3)) << 4);
    const char* wp[4][2];
    #pragma unroll
    for (int nt = 0; nt < 4; ++nt) {
        const char* base = wlds + (nt * 16 + lm) * 2048;
        wp[nt][0] = base + hb * 64 + L;            // even ks
        wp[nt][1] = base + (1 - hb) * 64 + L;      // odd ks
    }

    f32x4 acc[4];
    acc[0] = acc[1] = acc[2] = acc[3] = (f32x4){0.f, 0.f, 0.f, 0.f};
    XLoop<0>::run(XA, XB, xa, wp, acc);

    // ---- Ko via wave-local LDS transpose (no barrier: own tb[wid] only) -------
    #pragma unroll
    for (int nt = 0; nt < 4; ++nt)
        #pragma unroll
        for (int r = 0; r < 4; ++r)
            tb[wid][lg * 4 + r][nt * 16 + lm] =
                (unsigned short)(pk2(acc[nt][r], 0.f) & 0xffffu);
    const size_t m0r = (size_t)bid * 64 + wid * 16;
    {
        const char* tbase = (const char*)&tb[wid][0][0];
        i32x4 v0 = *(const i32x4*)(tbase + l * 16);          // rows 0..7
        i32x4 v1 = *(const i32x4*)(tbase + 1024 + l * 16);   // rows 8..15
        char* kbase = (char*)(Ko + m0r * HD);
        *(i32x4*)(kbase + l * 16)        = v0;
        *(i32x4*)(kbase + 1024 + l * 16) = v1;
    }
    const size_t g = (size_t)bid * 4 + wid;
    #pragma unroll
    for (int nt = 0; nt < 4; ++nt)
        KV2[(g * 4 + nt) * 64 + l] =
            make_uint2(pk2(acc[nt][0], acc[nt][1]), pk2(acc[nt][2], acc[nt][3]));
}

// ---------------- kernel 2: causal flash attention, 4 q-tiles / block -----------
// 256 blocks x 256 threads (4 waves). Block = (b, j): q-tiles
// {2j, 2j+1, 126-2j, 127-2j} — per-block loads (128-2j tiles) and compute
// (258 tile-computations) both ~constant. Wave w loads tiles ≡ w (mod 4) ONCE
// and applies them to every active q-slot (kt <= qts[s]; diag at equality).
// Same per-q-tile tile order as r14 -> bit-identical output.
struct KT { bf16x8 ka0, ka1; uint2 bv[4]; };

static __device__ __forceinline__ KT load_tile(const unsigned short* __restrict__ Kb,
                                               const uint2* __restrict__ KVb,
                                               int kt, int lm, int lg, int l) {
    KT t;
    const unsigned short* ar = Kb + (size_t)(kt * 16 + lm) * HD + lg * 8;
    t.ka0 = *(const bf16x8*)ar;
    t.ka1 = *(const bf16x8*)(ar + 32);
    const uint2* vp = KVb + (size_t)kt * 256 + l;
    #pragma unroll
    for (int nt = 0; nt < 4; ++nt) t.bv[nt] = vp[nt * 64];
    return t;
}

static __device__ __forceinline__ void proc_tile(const KT& t, bf16x8 bq0, bf16x8 bq1,
                                                 bool diag, int lm, int lg,
                                                 float& ls, f32x4 o[4]) {
    f32x4 s4 = (f32x4){0.f, 0.f, 0.f, 0.f};
    s4 = __builtin_amdgcn_mfma_f32_16x16x32_bf16(t.ka0, bq0, s4, 0, 0, 0);
    s4 = __builtin_amdgcn_mfma_f32_16x16x32_bf16(t.ka1, bq1, s4, 0, 0, 0);
    float s0 = s4[0], s1 = s4[1], s2 = s4[2], s3 = s4[3];
    if (diag) {
        const int kb = lg * 4;
        s0 = (kb + 0 > lm) ? -1e30f : s0;
        s1 = (kb + 1 > lm) ? -1e30f : s1;
        s2 = (kb + 2 > lm) ? -1e30f : s2;
        s3 = (kb + 3 > lm) ? -1e30f : s3;
    }
    float p0 = __builtin_amdgcn_exp2f(s0 * CEXP);
    float p1 = __builtin_amdgcn_exp2f(s1 * CEXP);
    float p2 = __builtin_amdgcn_exp2f(s2 * CEXP);
    float p3 = __builtin_amdgcn_exp2f(s3 * CEXP);
    ls += (p0 + p1) + (p2 + p3);
    i32x4 pw = { (int)pk2(p0, p1), (int)pk2(p2, p3), 0, 0 };
    bf16x8 pa = __builtin_bit_cast(bf16x8, pw);
    #pragma unroll
    for (int nt = 0; nt < 4; ++nt) {
        i32x4 vw = { (int)t.bv[nt].x, (int)t.bv[nt].y, 0, 0 };
        bf16x8 bvx = __builtin_bit_cast(bf16x8, vw);
        o[nt] = __builtin_amdgcn_mfma_f32_16x16x32_bf16(pa, bvx, o[nt], 0, 0, 0);
    }
}

__global__ __launch_bounds__(256, 1) void attn_kernel(const unsigned short* __restrict__ K,
                                                      const uint2* __restrict__ KV2,
                                                      float* __restrict__ out) {
    __shared__ float oS[4][4][16][68];   // [slot][wave][row][col] (~70 KB)
    __shared__ float lS[4][4][16];
    const int tid = threadIdx.x;
    const int wid = tid >> 6, l = tid & 63, lm = l & 15, lg = l >> 4;
    const int b = blockIdx.x >> 5, j = blockIdx.x & 31;
    const int qts[4] = { 2 * j, 2 * j + 1, 126 - 2 * j, 127 - 2 * j };
    const unsigned short* Kb  = K   + (size_t)b * SEQ * HD;
    const uint2*          KVb = KV2 + (size_t)b * 128 * 256;

    // per-slot Q B-frags (col = q-local = lm, k = d)
    bf16x8 bq0[4], bq1[4];
    #pragma unroll
    for (int s = 0; s < 4; ++s) {
        const unsigned short* qr = Kb + (size_t)(qts[s] * 16 + lm) * HD + lg * 8;
        bq0[s] = *(const bf16x8*)qr;
        bq1[s] = *(const bf16x8*)(qr + 32);
    }

    float ls[4] = { 0.f, 0.f, 0.f, 0.f };
    f32x4 o[4][4];
    #pragma unroll
    for (int s = 0; s < 4; ++s)
        #pragma unroll
        for (int nt = 0; nt < 4; ++nt) o[s][nt] = (f32x4){0.f, 0.f, 0.f, 0.f};

    auto process = [&](const KT& t, int kt) {
        #pragma unroll
        for (int s = 0; s < 4; ++s)
            if (kt <= qts[s])   // wave-uniform branch
                proc_tile(t, bq0[s], bq1[s], kt == qts[s], lm, lg, ls[s], o[s]);
    };

    // wave wid loads tiles ≡ wid (mod 4), depth-2 prefetch; qmax = qts[3] >= 65
    const int qmax = qts[3];
    KT A = load_tile(Kb, KVb, wid, lm, lg, l);
    int kt = wid;
    while (kt + 4 <= qmax) {
        KT B = load_tile(Kb, KVb, kt + 4, lm, lg, l);
        process(A, kt);
        A = B; kt += 4;
    }
    process(A, kt);

    // publish per-slot partials (ls reduced across the 4 lanes sharing q-col lm)
    #pragma unroll
    for (int s = 0; s < 4; ++s) {
        float lsum = ls[s];
        lsum += __shfl_xor(lsum, 16);
        lsum += __shfl_xor(lsum, 32);
        #pragma unroll
        for (int nt = 0; nt < 4; ++nt)
            #pragma unroll
            for (int r = 0; r < 4; ++r)
                oS[s][wid][lg * 4 + r][nt * 16 + lm] = o[s][nt][r];
        if (lg == 0) lS[s][wid][lm] = lsum;
    }
    __syncthreads();

    // combine: thread-group wid handles slot wid; thread = (row, 16-col group)
    const int slot = wid;
    const int row  = l >> 2;
    const int cg   = l & 3;
    const int qt   = (slot < 2) ? (2 * j + slot) : (126 - 2 * j + (slot - 2));
    float Lsum = lS[slot][0][row] + lS[slot][1][row] + lS[slot][2][row] + lS[slot][3][row];
    const float inv = 1.f / Lsum;
    float* op = out + ((size_t)b * SEQ + qt * 16 + row) * HD + cg * 16;
    #pragma unroll
    for (int q4 = 0; q4 < 4; ++q4) {
        f32x4 a = (f32x4){0.f, 0.f, 0.f, 0.f};
        #pragma unroll
        for (int w = 0; w < 4; ++w)
            a += *(const f32x4*)&oS[slot][w][row][cg * 16 + q4 * 4];
        *(f32x4*)(op + q4 * 4) = a * inv;
    }
}

extern "C" void kernel_launch(void* const* d_in, const int* in_sizes, int n_in,
                              void* d_out, int out_size, void* d_ws, size_t ws_size,
                              hipStream_t stream) {
    const float* x  = (const float*)d_in[0];   // [8,2048,1024] fp32
    const float* Wk = (const float*)d_in[1];   // [64,1024] fp32
    float* o        = (float*)d_out;           // [8,2048,64] fp32
    unsigned short* Kp = (unsigned short*)d_ws;              // bf16 K [16384][64] (2 MB)
    uint2* KV2 = (uint2*)(Kp + (size_t)NROW * HD);           // PV frags (2 MB)

    proj_kernel<<<256, 256, 0, stream>>>(x, Wk, Kp, KV2);
    attn_kernel<<<256, 256, 0, stream>>>(Kp, KV2, o);
}